// Round 5
// baseline (311.561 us; speedup 1.0000x reference)
//
#include <hip/hip_runtime.h>
#include <hip/hip_bf16.h>
#include <math.h>

// R15: softmax stage DELETED (5 launches -> 4). R14 post-mortem: ring/vmcnt
// micro-surgery on the 128^2 2-phase core is null (matches m196/m218: T4 only
// pays inside T3's fine interleave); remaining waste is structural.
// New: scores epilogue emits per-(row, n-tile) stats (masked max, sumexp);
// pv prologue combines them to M_row, 1/L_row; pv A-operand is reg-staged
// from S f32 with p = mask ? exp(s-M) : 0 -> bf16 -> ds_write into the same
// swizzled LDS slots (read side unchanged); out = acc * (1/L) in f32 epilogue
// (numerically >= old bf16(p/l)). P buffer gone; S/P roundtrip traffic -20MiB.
// qkv/cvt untouched (qkv 85.5-98.4 on identical code across R11-R14 = +-7%
// cross-run clock noise; its MfmaUtil steady 21-24%).
// Core layout: 128x128 tile, BK=32, width=16 global_load_lds into contiguous
// [128][32] LDS, slot c holds k-chunk c^((row>>1)&3); reads use
// quad^((row>>1)&3). mfma_f32_16x16x32_bf16 (layouts verified m89/m91).

typedef __bf16 bf16x8 __attribute__((ext_vector_type(8)));
typedef float  f32x4  __attribute__((ext_vector_type(4)));

__device__ __forceinline__ ushort f2bf(float f) {
    __hip_bfloat16 h = __float2bfloat16(f);
    return *reinterpret_cast<ushort*>(&h);
}

__device__ __forceinline__ void async_load16(const ushort* g, ushort* l) {
    __builtin_amdgcn_global_load_lds(
        (const __attribute__((address_space(1))) void*)g,
        (__attribute__((address_space(3))) void*)l, 16, 0, 0);
}

// Stage 8 f32 -> masked exp -> bf16x8 -> one ds_write_b128.
__device__ __forceinline__ void stage_a16(
    ushort* dst, float4 lo, float4 hi, float m, int nv)
{
    float s[8] = {lo.x, lo.y, lo.z, lo.w, hi.x, hi.y, hi.z, hi.w};
    ushort o[8];
#pragma unroll
    for (int u = 0; u < 8; ++u) {
        const float e = (u < nv) ? __expf(s[u] - m) : 0.0f;
        o[u] = f2bf(e);
    }
    *(int4*)dst = *(const int4*)o;
}

// One launch for all 4 fp32->bf16 conversions + RoPE cos/sin table.
// grid (8192, 5): y<4 = conversions, y==4 = table gen (first 4096 x-blocks).
__global__ __launch_bounds__(256) void cvt_all_kernel(
    const float* __restrict__ x,  const float* __restrict__ wq,
    const float* __restrict__ wk, const float* __restrict__ wv,
    ushort* __restrict__ xb, ushort* __restrict__ wqb,
    ushort* __restrict__ wkb, ushort* __restrict__ wvb,
    float2* __restrict__ cs)
{
    const int t = blockIdx.y;
    if (t == 4) {
        // RoPE table: cs[pos*512 + i] = (cos(pos*phi_i), sin(pos*phi_i)),
        // phi_i = 10000^(-2*(i-1)/1024)  (reference's -1 quirk preserved).
        const int idx = blockIdx.x * 256 + threadIdx.x;
        if (idx < 2048 * 512) {
            const int pos = idx >> 9, i = idx & 511;
            const float phi = powf(10000.0f, -2.0f * ((float)i - 1.0f) / 1024.0f);
            float s, c;
            sincosf((float)pos * phi, &s, &c);
            cs[idx] = make_float2(c, s);
        }
        return;
    }
    const float* in  = (t == 0) ? x  : (t == 1) ? wq  : (t == 2) ? wk  : wv;
    ushort*      out = (t == 0) ? xb : (t == 1) ? wqb : (t == 2) ? wkb : wvb;
    const int n4 = (t == 0) ? 2097152 : 262144;
    int i = blockIdx.x * blockDim.x + threadIdx.x;
    if (i < n4) {
        float4 f = ((const float4*)in)[i];
        ushort4 o;
        o.x = f2bf(f.x); o.y = f2bf(f.y); o.z = f2bf(f.z); o.w = f2bf(f.w);
        ((ushort4*)out)[i] = o;
    }
}

// ---------------- single-buffer core (R11): for high-occupancy kernels ----
__device__ __forceinline__ void gemm128_core_sb(
    const ushort* __restrict__ A, const ushort* __restrict__ B,
    int lda, int ldb, int m0, int n0, int kIters,
    ushort* As, ushort* Bs, f32x4 acc[4][4])
{
    const int tid  = threadIdx.x;
    const int lane = tid & 63, wave = tid >> 6;
    const int wm = (wave >> 1) * 64, wn = (wave & 1) * 64;
    const int quad = lane >> 4, l16 = lane & 15;
    const int srow = lane >> 2, c = lane & 3;
    const int rr   = wave * 32 + srow;
    const int cc   = c ^ ((rr >> 1) & 3);
    const int scol = cc * 8;

    const ushort* ag0 = A + (size_t)(m0 + rr) * lda + scol;
    const ushort* bg0 = B + (size_t)(n0 + rr) * ldb + scol;
    const ushort* ag1 = ag0 + (size_t)16 * lda;
    const ushort* bg1 = bg0 + (size_t)16 * ldb;
    ushort* la0 = As + (wave * 32) * 32;
    ushort* la1 = la0 + 16 * 32;
    ushort* lb0 = Bs + (wave * 32) * 32;
    ushort* lb1 = lb0 + 16 * 32;

    for (int kt = 0; kt < kIters; ++kt) {
        const int k0 = kt * 32;
        async_load16(ag0 + k0, la0);
        async_load16(ag1 + k0, la1);
        async_load16(bg0 + k0, lb0);
        async_load16(bg1 + k0, lb1);
        __syncthreads();
        bf16x8 aF[4], bF[4];
#pragma unroll
        for (int i = 0; i < 4; ++i) {
            const int r = wm + i * 16 + l16;
            aF[i] = *(const bf16x8*)(As + r * 32 + ((quad ^ ((r >> 1) & 3)) * 8));
        }
#pragma unroll
        for (int j = 0; j < 4; ++j) {
            const int r = wn + j * 16 + l16;
            bF[j] = *(const bf16x8*)(Bs + r * 32 + ((quad ^ ((r >> 1) & 3)) * 8));
        }
#pragma unroll
        for (int i = 0; i < 4; ++i)
#pragma unroll
            for (int j = 0; j < 4; ++j)
                acc[i][j] = __builtin_amdgcn_mfma_f32_16x16x32_bf16(aF[i], bF[j], acc[i][j], 0, 0, 0);
        __syncthreads();
    }
}

// ------------- 3-buffer ring core with counted vmcnt (scores) -------------
__device__ __forceinline__ void gemm128_core_ring(
    const ushort* __restrict__ A, const ushort* __restrict__ B,
    int lda, int ldb, int m0, int n0, int kIters,
    ushort* L, f32x4 acc[4][4])
{
    const int tid  = threadIdx.x;
    const int lane = tid & 63, wave = tid >> 6;
    const int wm = (wave >> 1) * 64, wn = (wave & 1) * 64;
    const int quad = lane >> 4, l16 = lane & 15;
    const int srow = lane >> 2, c = lane & 3;
    const int rr   = wave * 32 + srow;
    const int cc   = c ^ ((rr >> 1) & 3);
    const int scol = cc * 8;

    const ushort* ag0 = A + (size_t)(m0 + rr) * lda + scol;
    const ushort* bg0 = B + (size_t)(n0 + rr) * ldb + scol;
    const ushort* ag1 = ag0 + (size_t)16 * lda;
    const ushort* bg1 = bg0 + (size_t)16 * ldb;
    const int lofs = (wave * 32) * 32;

#define RING_STAGE(KT, BUF) do {                                   \
        const int _k0 = (KT) * 32;                                 \
        ushort* _la = L + (BUF) * 4096 + lofs;                     \
        ushort* _lb = L + 12288 + (BUF) * 4096 + lofs;             \
        async_load16(ag0 + _k0, _la);                              \
        async_load16(ag1 + _k0, _la + 16 * 32);                    \
        async_load16(bg0 + _k0, _lb);                              \
        async_load16(bg1 + _k0, _lb + 16 * 32);                    \
    } while (0)

    RING_STAGE(0, 0);
    if (kIters > 1) RING_STAGE(1, 1);

    int buf = 0;
    for (int kt = 0; kt < kIters; ++kt) {
        if (kt + 1 < kIters) {
            asm volatile("s_waitcnt vmcnt(4)" ::: "memory");
        } else {
            asm volatile("s_waitcnt vmcnt(0)" ::: "memory");
        }
        __builtin_amdgcn_s_barrier();
        asm volatile("" ::: "memory");
        if (kt + 2 < kIters) {
            int nb = buf + 2; if (nb >= 3) nb -= 3;
            RING_STAGE(kt + 2, nb);
        }
        const ushort* as = L + buf * 4096;
        const ushort* bs = L + 12288 + buf * 4096;
        bf16x8 aF[4], bF[4];
#pragma unroll
        for (int i = 0; i < 4; ++i) {
            const int r = wm + i * 16 + l16;
            aF[i] = *(const bf16x8*)(as + r * 32 + ((quad ^ ((r >> 1) & 3)) * 8));
        }
#pragma unroll
        for (int j = 0; j < 4; ++j) {
            const int r = wn + j * 16 + l16;
            bF[j] = *(const bf16x8*)(bs + r * 32 + ((quad ^ ((r >> 1) & 3)) * 8));
        }
#pragma unroll
        for (int i = 0; i < 4; ++i)
#pragma unroll
            for (int j = 0; j < 4; ++j)
                acc[i][j] = __builtin_amdgcn_mfma_f32_16x16x32_bf16(aF[i], bF[j], acc[i][j], 0, 0, 0);
        buf += 1; if (buf == 3) buf = 0;
    }
#undef RING_STAGE
}

#define ACC_INIT4(acc) \
    _Pragma("unroll") for (int i = 0; i < 4; ++i) \
    _Pragma("unroll") for (int j = 0; j < 4; ++j) \
    _Pragma("unroll") for (int r = 0; r < 4; ++r) acc[i][j][r] = 0.0f;

// QKV + RoPE, z-split. grid (64, 8, 3). Single-buffer core (5 blocks/CU).
__global__ __launch_bounds__(256) void qkv_rope_kernel(
    const ushort* __restrict__ xb, const ushort* __restrict__ wq,
    const ushort* __restrict__ wk, const ushort* __restrict__ wv,
    const float2* __restrict__ cs,
    ushort* __restrict__ Qr, ushort* __restrict__ Kr, ushort* __restrict__ VT)
{
    __shared__ __attribute__((aligned(16))) ushort As[128 * 32];
    __shared__ __attribute__((aligned(16))) ushort Bs[128 * 32];
    const int m0 = blockIdx.x * 128;
    const int n0 = blockIdx.y * 128;
    const int z  = blockIdx.z;
    const ushort* W = (z == 0) ? wq : (z == 1) ? wk : wv;

    f32x4 acc[4][4];
    ACC_INIT4(acc)
    gemm128_core_sb(xb, W, 1024, 1024, m0, n0, 32, As, Bs, acc);

    const int lane = threadIdx.x & 63, wave = threadIdx.x >> 6;
    const int wm = (wave >> 1) * 64, wn = (wave & 1) * 64;
    const int quad = lane >> 4, l16 = lane & 15;

    if (z < 2) {
        ushort* out = (z == 0) ? Qr : Kr;
#pragma unroll
        for (int j = 0; j < 4; ++j) {
            const int n = n0 + wn + j * 16 + l16;
            const int iidx = n >> 1;
            const bool odd = n & 1;
#pragma unroll
            for (int i = 0; i < 4; ++i) {
                const int mbase = m0 + wm + i * 16 + quad * 4;
                const int pos0  = mbase & 2047;
                const float2* csp = cs + (size_t)pos0 * 512 + iidx;
#pragma unroll
                for (int r = 0; r < 4; ++r) {
                    const float2 sc = csp[(size_t)r * 512]; // (cos, sin) at pos0+r
                    float v = acc[i][j][r];
                    float p = __shfl_xor(v, 1);   // partner column n^1, same row
                    float o = odd ? (v * sc.x - p * sc.y) : (v * sc.x + p * sc.y);
                    out[(size_t)(mbase + r) * 1024 + n] = f2bf(o);
                }
            }
        }
    } else {
        // V transposed: VT[b][n][pos]; 4 consecutive pos per quad -> ushort4
#pragma unroll
        for (int i = 0; i < 4; ++i) {
            const int mbase = m0 + wm + i * 16 + quad * 4;
            const int b = mbase >> 11, pos0 = mbase & 2047;
#pragma unroll
            for (int j = 0; j < 4; ++j) {
                const int n = n0 + wn + j * 16 + l16;
                ushort4 o;
                o.x = f2bf(acc[i][j][0]); o.y = f2bf(acc[i][j][1]);
                o.z = f2bf(acc[i][j][2]); o.w = f2bf(acc[i][j][3]);
                *(ushort4*)(VT + ((size_t)b * 1024 + n) * 2048 + pos0) = o;
            }
        }
    }
}

// scores: grid (16, 16, 4); lower tiles only; S fp32 scaled 1/32; also emits
// per-(row, n-tile) stats: Smax = masked row max, Ssum = sum exp(s - Smax).
__global__ __launch_bounds__(256) void scores_kernel(
    const ushort* __restrict__ Qr, const ushort* __restrict__ Kr,
    float* __restrict__ S, float* __restrict__ Smax, float* __restrict__ Ssum)
{
    const int m0 = blockIdx.x * 128;
    const int n0 = blockIdx.y * 128;
    if (n0 > m0 + 127) return;
    const int b = blockIdx.z;
    __shared__ __attribute__((aligned(16))) ushort L[6 * 4096];  // 48 KB
    __shared__ float scrM[128][2];
    __shared__ float scrS[128][2];
    const ushort* A = Qr + (size_t)b * 2048 * 1024;
    const ushort* B = Kr + (size_t)b * 2048 * 1024;
    float* Sb = S + (size_t)b * 2048 * 2048;

    f32x4 acc[4][4];
    ACC_INIT4(acc)
    gemm128_core_ring(A, B, 1024, 1024, m0, n0, 32, L, acc);

    const int lane = threadIdx.x & 63, wave = threadIdx.x >> 6;
    const int wm = (wave >> 1) * 64, wn = (wave & 1) * 64;
    const int quad = lane >> 4, l16 = lane & 15;
#pragma unroll
    for (int i = 0; i < 4; ++i)
#pragma unroll
        for (int j = 0; j < 4; ++j) {
            const int n = n0 + wn + j * 16 + l16;
#pragma unroll
            for (int r = 0; r < 4; ++r) {
                const int m = m0 + wm + i * 16 + quad * 4 + r;
                Sb[(size_t)m * 2048 + n] = acc[i][j][r] * 0.03125f;
            }
        }

    // ---- per-tile row stats for fused-softmax pv ----
    const int relq  = wm + quad * 4;          // + i*16 + r = rel row
    const int gcol0 = n0 + wn + l16;          // + j*16 = global col
    float tm[4][4];
    // phase 1: masked max over this block's 128 cols (j regs + l16 lanes + 2 halves)
#pragma unroll
    for (int i = 0; i < 4; ++i)
#pragma unroll
        for (int r = 0; r < 4; ++r) {
            const int grow = m0 + relq + i * 16 + r;
            float mv = -3.402823466e38f;
#pragma unroll
            for (int j = 0; j < 4; ++j)
                if (gcol0 + j * 16 <= grow) mv = fmaxf(mv, acc[i][j][r] * 0.03125f);
#pragma unroll
            for (int d = 1; d < 16; d <<= 1) mv = fmaxf(mv, __shfl_xor(mv, d));
            if (l16 == 0) scrM[relq + i * 16 + r][wave & 1] = mv;
        }
    __syncthreads();
#pragma unroll
    for (int i = 0; i < 4; ++i)
#pragma unroll
        for (int r = 0; r < 4; ++r) {
            const int rel = relq + i * 16 + r;
            tm[i][r] = fmaxf(scrM[rel][0], scrM[rel][1]);
        }
    // phase 2: masked sum of exp(s - tilemax)
#pragma unroll
    for (int i = 0; i < 4; ++i)
#pragma unroll
        for (int r = 0; r < 4; ++r) {
            const int grow = m0 + relq + i * 16 + r;
            float ps = 0.0f;
#pragma unroll
            for (int j = 0; j < 4; ++j)
                if (gcol0 + j * 16 <= grow)
                    ps += __expf(acc[i][j][r] * 0.03125f - tm[i][r]);
#pragma unroll
            for (int d = 1; d < 16; d <<= 1) ps += __shfl_xor(ps, d);
            if (l16 == 0) scrS[relq + i * 16 + r][wave & 1] = ps;
        }
    __syncthreads();
    if ((wave & 1) == 0 && l16 == 0) {
        const int nt = blockIdx.y;
#pragma unroll
        for (int i = 0; i < 4; ++i)
#pragma unroll
            for (int r = 0; r < 4; ++r) {
                const int rel = relq + i * 16 + r;
                const size_t sidx = ((size_t)b * 16 + nt) * 2048 + (m0 + rel);
                Smax[sidx] = tm[i][r];
                Ssum[sidx] = scrS[rel][0] + scrS[rel][1];
            }
    }
}

// pv with fused softmax: grid (16, 8, 4); causal k-limit; m-tile interleave.
// A staged from S f32 via reg: p = mask ? exp(s - M_row) : 0 -> bf16 -> LDS.
// Output normalized by 1/L_row in f32 epilogue.
__global__ __launch_bounds__(256) void pv_kernel(
    const float* __restrict__ S, const ushort* __restrict__ VT,
    const float* __restrict__ Smax, const float* __restrict__ Ssum,
    float* __restrict__ out)
{
    __shared__ __attribute__((aligned(16))) ushort Abuf[2 * 4096];
    __shared__ __attribute__((aligned(16))) ushort Bbuf[2 * 4096];
    __shared__ float Mli[128][2];
    const int x  = blockIdx.x;
    const int mt = (x & 1) ? (15 - (x >> 1)) : (x >> 1);  // 0,15,1,14,...
    const int m0 = mt * 128;
    const int n0 = blockIdx.y * 128;
    const int b  = blockIdx.z;
    const float*  Sb = S + (size_t)b * 2048 * 2048;
    const ushort* B  = VT + (size_t)b * 1024 * 2048;
    const int kIters = (m0 + 128) / 32;   // causal: cols beyond m0+127 unused
    const int tid = threadIdx.x;

    // ---- combine per-row stats: M = max of tile maxes, L = rescaled sum ----
    if (tid < 128) {
        const size_t sb0 = (size_t)b * 16 * 2048 + (m0 + tid);
        float M = -3.402823466e38f;
        for (int nt = 0; nt <= mt; ++nt)
            M = fmaxf(M, Smax[sb0 + (size_t)nt * 2048]);
        float Ls = 0.0f;
        for (int nt = 0; nt <= mt; ++nt)
            Ls += Ssum[sb0 + (size_t)nt * 2048] *
                  __expf(Smax[sb0 + (size_t)nt * 2048] - M);
        Mli[tid][0] = M;
        Mli[tid][1] = 1.0f / Ls;
    }
    __syncthreads();

    const int lane = tid & 63, wave = tid >> 6;
    const int wm = (wave >> 1) * 64, wn = (wave & 1) * 64;
    const int quad = lane >> 4, l16 = lane & 15;
    const int srow = lane >> 2, c = lane & 3;
    const int rr   = wave * 32 + srow;
    const int cc   = c ^ ((rr >> 1) & 3);
    const int scol = cc * 8;

    const float*  sA0 = Sb + (size_t)(m0 + rr) * 2048 + scol;
    const float*  sA1 = sA0 + (size_t)16 * 2048;
    const ushort* bg0 = B + (size_t)(n0 + rr) * 2048 + scol;
    const ushort* bg1 = bg0 + (size_t)16 * 2048;
    const int ofs = wave * 1024 + lane * 8;   // ushort offset of this lane's slot
    const float mr0 = Mli[rr][0];
    const float mr1 = Mli[rr + 16][0];
    const int vr0 = m0 + rr;                  // global rows for causal mask
    const int vr1 = m0 + rr + 16;

    f32x4 acc[4][4];
    ACC_INIT4(acc)

    // Prologue: stage tile 0 (A via reg+exp, B async), then barrier.
    {
        float4 a0 = *(const float4*)(sA0);
        float4 a1 = *(const float4*)(sA0 + 4);
        float4 a2 = *(const float4*)(sA1);
        float4 a3 = *(const float4*)(sA1 + 4);
        stage_a16(Abuf + ofs,       a0, a1, mr0, vr0 - scol + 1);
        stage_a16(Abuf + ofs + 512, a2, a3, mr1, vr1 - scol + 1);
        async_load16(bg0, Bbuf + ofs);
        async_load16(bg1, Bbuf + ofs + 512);
    }
    __syncthreads();

    int cur = 0;
    for (int kt = 0; kt < kIters; ++kt) {
        float4 p0, p1, p2, p3;
        const bool hn = (kt + 1 < kIters);
        const int k1 = (kt + 1) * 32;
        if (hn) {
            // Issue next A-tile f32 loads (regs) + next B-tile async early;
            // both have the whole MFMA phase to cover their latency.
            p0 = *(const float4*)(sA0 + k1);
            p1 = *(const float4*)(sA0 + k1 + 4);
            p2 = *(const float4*)(sA1 + k1);
            p3 = *(const float4*)(sA1 + k1 + 4);
            async_load16(bg0 + k1, Bbuf + (cur ^ 1) * 4096 + ofs);
            async_load16(bg1 + k1, Bbuf + (cur ^ 1) * 4096 + ofs + 512);
        }
        const ushort* as = Abuf + cur * 4096;
        const ushort* bs = Bbuf + cur * 4096;
        bf16x8 aF[4], bF[4];
#pragma unroll
        for (int i = 0; i < 4; ++i) {
            const int r = wm + i * 16 + l16;
            aF[i] = *(const bf16x8*)(as + r * 32 + ((quad ^ ((r >> 1) & 3)) * 8));
        }
#pragma unroll
        for (int j = 0; j < 4; ++j) {
            const int r = wn + j * 16 + l16;
            bF[j] = *(const bf16x8*)(bs + r * 32 + ((quad ^ ((r >> 1) & 3)) * 8));
        }
#pragma unroll
        for (int i = 0; i < 4; ++i)
#pragma unroll
            for (int j = 0; j < 4; ++j)
                acc[i][j] = __builtin_amdgcn_mfma_f32_16x16x32_bf16(aF[i], bF[j], acc[i][j], 0, 0, 0);
        if (hn) {
            // exp+pack+ds_write next A-tile into buf^1 (last read iter kt-1,
            // barrier since then -> WAR safe; end barrier makes it visible).
            stage_a16(Abuf + (cur ^ 1) * 4096 + ofs,       p0, p1, mr0, vr0 - k1 - scol + 1);
            stage_a16(Abuf + (cur ^ 1) * 4096 + ofs + 512, p2, p3, mr1, vr1 - k1 - scol + 1);
        }
        __syncthreads();   // drains lgkm (A writes) + vmcnt (B async)
        cur ^= 1;
    }

#pragma unroll
    for (int i = 0; i < 4; ++i)
#pragma unroll
        for (int j = 0; j < 4; ++j) {
            const int n = n0 + wn + j * 16 + l16;
#pragma unroll
            for (int r = 0; r < 4; ++r) {
                const int rel = wm + i * 16 + quad * 4 + r;
                const int m = m0 + rel;
                out[((size_t)b * 2048 + m) * 1024 + n] = acc[i][j][r] * Mli[rel][1];
            }
        }
}

extern "C" void kernel_launch(void* const* d_in, const int* in_sizes, int n_in,
                              void* d_out, int out_size, void* d_ws, size_t ws_size,
                              hipStream_t stream) {
    const float* x  = (const float*)d_in[0];
    const float* wq = (const float*)d_in[1];
    const float* wk = (const float*)d_in[2];
    const float* wv = (const float*)d_in[3];

    const size_t MiB = 1024 * 1024;
    char* ws = (char*)d_ws;
    ushort* xb  = (ushort*)(ws);              //  16 MiB [8192][1024] bf16
    ushort* wqb = (ushort*)(ws +  16 * MiB);  //   2 MiB
    ushort* wkb = (ushort*)(ws +  18 * MiB);  //   2 MiB
    ushort* wvb = (ushort*)(ws +  20 * MiB);  //   2 MiB
    ushort* Qr  = (ushort*)(ws +  22 * MiB);  //  16 MiB [4][2048][1024] bf16
    ushort* Kr  = (ushort*)(ws +  38 * MiB);  //  16 MiB
    ushort* VT  = (ushort*)(ws +  54 * MiB);  //  16 MiB [4][1024][2048] bf16
    float*  S   = (float* )(ws +  70 * MiB);  //  64 MiB [4][2048][2048] f32
    float*  Smax= (float* )(ws + 134 * MiB);  // 512 KiB [4][16][2048] f32
    float*  Ssum= (float* )(ws + 135 * MiB);  // 512 KiB
    float2* cs  = (float2*)(ws + 166 * MiB);  //   8 MiB [2048][512] (cos,sin) f32
    float*  out = (float*)d_out;              // ws use: 174 MiB (256 avail)

    cvt_all_kernel <<<dim3(8192, 5),   256, 0, stream>>>(x, wq, wk, wv, xb, wqb, wkb, wvb, cs);
    qkv_rope_kernel<<<dim3(64, 8, 3),  256, 0, stream>>>(xb, wqb, wkb, wvb, cs, Qr, Kr, VT);
    scores_kernel  <<<dim3(16, 16, 4), 256, 0, stream>>>(Qr, Kr, S, Smax, Ssum);
    pv_kernel      <<<dim3(16, 8, 4),  256, 0, stream>>>(S, VT, Smax, Ssum, out);
}

// Round 6
// 274.720 us; speedup vs baseline: 1.1341x; 1.1341x over previous
//
#include <hip/hip_runtime.h>
#include <hip/hip_bf16.h>
#include <math.h>

// R16: consolidation. R15 post-mortem: fused-softmax pv regressed +40us
// (S f32 read x8 n-block redundancy ~+143MB, exp/pack replicated 8x on pv's
// critical path, stats epilogue barriers in scores) -> REVERTED to the
// compact-P pipeline. Best-known parts: R11 cvt + R11 qkv (single-buffer
// core; dbuf/ring both null-to-negative there), R13 scores/pv (plain dbuf
// core; R14 ring cost ~8us net-of-qkv vs dbuf), pv m-interleave.
// New this round: softmax reduction rewritten wave-parallel (__shfl_xor
// width-64 + 4-partial LDS combine = 3 barriers vs ~18 of the 256-thread
// LDS tree). Known facts: qkv cross-run noise band 85.5-98.4 on identical
// code (+-7%); qkv VGPR=92 -> 4 blocks/CU fixed (m69 quantization, no
// occupancy lever above 64 VGPR); counted-vmcnt grafts on 2-phase loops are
// null (m196/m218). Core layout: 128x128 tile, BK=32, width=16
// global_load_lds into contiguous [128][32] LDS, slot c holds k-chunk
// c^((row>>1)&3); reads use quad^((row>>1)&3). mfma_f32_16x16x32_bf16
// (layouts verified m89/m91).

typedef __bf16 bf16x8 __attribute__((ext_vector_type(8)));
typedef float  f32x4  __attribute__((ext_vector_type(4)));

__device__ __forceinline__ ushort f2bf(float f) {
    __hip_bfloat16 h = __float2bfloat16(f);
    return *reinterpret_cast<ushort*>(&h);
}

__device__ __forceinline__ void async_load16(const ushort* g, ushort* l) {
    __builtin_amdgcn_global_load_lds(
        (const __attribute__((address_space(1))) void*)g,
        (__attribute__((address_space(3))) void*)l, 16, 0, 0);
}

// One launch for all 4 fp32->bf16 conversions + RoPE cos/sin table.
// grid (8192, 5): y<4 = conversions, y==4 = table gen (first 4096 x-blocks).
__global__ __launch_bounds__(256) void cvt_all_kernel(
    const float* __restrict__ x,  const float* __restrict__ wq,
    const float* __restrict__ wk, const float* __restrict__ wv,
    ushort* __restrict__ xb, ushort* __restrict__ wqb,
    ushort* __restrict__ wkb, ushort* __restrict__ wvb,
    float2* __restrict__ cs)
{
    const int t = blockIdx.y;
    if (t == 4) {
        // RoPE table: cs[pos*512 + i] = (cos(pos*phi_i), sin(pos*phi_i)),
        // phi_i = 10000^(-2*(i-1)/1024)  (reference's -1 quirk preserved).
        const int idx = blockIdx.x * 256 + threadIdx.x;
        if (idx < 2048 * 512) {
            const int pos = idx >> 9, i = idx & 511;
            const float phi = powf(10000.0f, -2.0f * ((float)i - 1.0f) / 1024.0f);
            float s, c;
            sincosf((float)pos * phi, &s, &c);
            cs[idx] = make_float2(c, s);
        }
        return;
    }
    const float* in  = (t == 0) ? x  : (t == 1) ? wq  : (t == 2) ? wk  : wv;
    ushort*      out = (t == 0) ? xb : (t == 1) ? wqb : (t == 2) ? wkb : wvb;
    const int n4 = (t == 0) ? 2097152 : 262144;
    int i = blockIdx.x * blockDim.x + threadIdx.x;
    if (i < n4) {
        float4 f = ((const float4*)in)[i];
        ushort4 o;
        o.x = f2bf(f.x); o.y = f2bf(f.y); o.z = f2bf(f.z); o.w = f2bf(f.w);
        ((ushort4*)out)[i] = o;
    }
}

// ---------------- single-buffer core (R11): for high-occupancy kernels ----
__device__ __forceinline__ void gemm128_core_sb(
    const ushort* __restrict__ A, const ushort* __restrict__ B,
    int lda, int ldb, int m0, int n0, int kIters,
    ushort* As, ushort* Bs, f32x4 acc[4][4])
{
    const int tid  = threadIdx.x;
    const int lane = tid & 63, wave = tid >> 6;
    const int wm = (wave >> 1) * 64, wn = (wave & 1) * 64;
    const int quad = lane >> 4, l16 = lane & 15;
    const int srow = lane >> 2, c = lane & 3;
    const int rr   = wave * 32 + srow;
    const int cc   = c ^ ((rr >> 1) & 3);
    const int scol = cc * 8;

    const ushort* ag0 = A + (size_t)(m0 + rr) * lda + scol;
    const ushort* bg0 = B + (size_t)(n0 + rr) * ldb + scol;
    const ushort* ag1 = ag0 + (size_t)16 * lda;
    const ushort* bg1 = bg0 + (size_t)16 * ldb;
    ushort* la0 = As + (wave * 32) * 32;
    ushort* la1 = la0 + 16 * 32;
    ushort* lb0 = Bs + (wave * 32) * 32;
    ushort* lb1 = lb0 + 16 * 32;

    for (int kt = 0; kt < kIters; ++kt) {
        const int k0 = kt * 32;
        async_load16(ag0 + k0, la0);
        async_load16(ag1 + k0, la1);
        async_load16(bg0 + k0, lb0);
        async_load16(bg1 + k0, lb1);
        __syncthreads();
        bf16x8 aF[4], bF[4];
#pragma unroll
        for (int i = 0; i < 4; ++i) {
            const int r = wm + i * 16 + l16;
            aF[i] = *(const bf16x8*)(As + r * 32 + ((quad ^ ((r >> 1) & 3)) * 8));
        }
#pragma unroll
        for (int j = 0; j < 4; ++j) {
            const int r = wn + j * 16 + l16;
            bF[j] = *(const bf16x8*)(Bs + r * 32 + ((quad ^ ((r >> 1) & 3)) * 8));
        }
#pragma unroll
        for (int i = 0; i < 4; ++i)
#pragma unroll
            for (int j = 0; j < 4; ++j)
                acc[i][j] = __builtin_amdgcn_mfma_f32_16x16x32_bf16(aF[i], bF[j], acc[i][j], 0, 0, 0);
        __syncthreads();
    }
}

// ---------------- double-buffered core (R12/R13): low-occupancy kernels ---
__device__ __forceinline__ void gemm128_core_db(
    const ushort* __restrict__ A, const ushort* __restrict__ B,
    int lda, int ldb, int m0, int n0, int kIters,
    ushort* As, ushort* Bs, f32x4 acc[4][4])
{
    const int tid  = threadIdx.x;
    const int lane = tid & 63, wave = tid >> 6;
    const int wm = (wave >> 1) * 64, wn = (wave & 1) * 64;
    const int quad = lane >> 4, l16 = lane & 15;
    const int srow = lane >> 2, c = lane & 3;
    const int rr   = wave * 32 + srow;
    const int cc   = c ^ ((rr >> 1) & 3);
    const int scol = cc * 8;

    const ushort* ag0 = A + (size_t)(m0 + rr) * lda + scol;
    const ushort* bg0 = B + (size_t)(n0 + rr) * ldb + scol;
    const ushort* ag1 = ag0 + (size_t)16 * lda;
    const ushort* bg1 = bg0 + (size_t)16 * ldb;
    const int lofs = (wave * 32) * 32;

    // Prologue: stage k-tile 0 into buffer 0.
    async_load16(ag0, As + lofs);
    async_load16(ag1, As + lofs + 16 * 32);
    async_load16(bg0, Bs + lofs);
    async_load16(bg1, Bs + lofs + 16 * 32);
    __syncthreads();

    int cur = 0;
    for (int kt = 0; kt < kIters; ++kt) {
        if (kt + 1 < kIters) {
            const int k1 = (kt + 1) * 32;
            const int nb = (cur ^ 1) * 4096;
            async_load16(ag0 + k1, As + nb + lofs);
            async_load16(ag1 + k1, As + nb + lofs + 16 * 32);
            async_load16(bg0 + k1, Bs + nb + lofs);
            async_load16(bg1 + k1, Bs + nb + lofs + 16 * 32);
        }
        const ushort* as = As + cur * 4096;
        const ushort* bs = Bs + cur * 4096;
        bf16x8 aF[4], bF[4];
#pragma unroll
        for (int i = 0; i < 4; ++i) {
            const int r = wm + i * 16 + l16;
            aF[i] = *(const bf16x8*)(as + r * 32 + ((quad ^ ((r >> 1) & 3)) * 8));
        }
#pragma unroll
        for (int j = 0; j < 4; ++j) {
            const int r = wn + j * 16 + l16;
            bF[j] = *(const bf16x8*)(bs + r * 32 + ((quad ^ ((r >> 1) & 3)) * 8));
        }
#pragma unroll
        for (int i = 0; i < 4; ++i)
#pragma unroll
            for (int j = 0; j < 4; ++j)
                acc[i][j] = __builtin_amdgcn_mfma_f32_16x16x32_bf16(aF[i], bF[j], acc[i][j], 0, 0, 0);
        __syncthreads();
        cur ^= 1;
    }
}

#define ACC_INIT4(acc) \
    _Pragma("unroll") for (int i = 0; i < 4; ++i) \
    _Pragma("unroll") for (int j = 0; j < 4; ++j) \
    _Pragma("unroll") for (int r = 0; r < 4; ++r) acc[i][j][r] = 0.0f;

// QKV + RoPE, z-split. grid (64, 8, 3). Single-buffer core.
__global__ __launch_bounds__(256) void qkv_rope_kernel(
    const ushort* __restrict__ xb, const ushort* __restrict__ wq,
    const ushort* __restrict__ wk, const ushort* __restrict__ wv,
    const float2* __restrict__ cs,
    ushort* __restrict__ Qr, ushort* __restrict__ Kr, ushort* __restrict__ VT)
{
    __shared__ __attribute__((aligned(16))) ushort As[128 * 32];
    __shared__ __attribute__((aligned(16))) ushort Bs[128 * 32];
    const int m0 = blockIdx.x * 128;
    const int n0 = blockIdx.y * 128;
    const int z  = blockIdx.z;
    const ushort* W = (z == 0) ? wq : (z == 1) ? wk : wv;

    f32x4 acc[4][4];
    ACC_INIT4(acc)
    gemm128_core_sb(xb, W, 1024, 1024, m0, n0, 32, As, Bs, acc);

    const int lane = threadIdx.x & 63, wave = threadIdx.x >> 6;
    const int wm = (wave >> 1) * 64, wn = (wave & 1) * 64;
    const int quad = lane >> 4, l16 = lane & 15;

    if (z < 2) {
        ushort* out = (z == 0) ? Qr : Kr;
#pragma unroll
        for (int j = 0; j < 4; ++j) {
            const int n = n0 + wn + j * 16 + l16;
            const int iidx = n >> 1;
            const bool odd = n & 1;
#pragma unroll
            for (int i = 0; i < 4; ++i) {
                const int mbase = m0 + wm + i * 16 + quad * 4;
                const int pos0  = mbase & 2047;
                const float2* csp = cs + (size_t)pos0 * 512 + iidx;
#pragma unroll
                for (int r = 0; r < 4; ++r) {
                    const float2 sc = csp[(size_t)r * 512]; // (cos, sin) at pos0+r
                    float v = acc[i][j][r];
                    float p = __shfl_xor(v, 1);   // partner column n^1, same row
                    float o = odd ? (v * sc.x - p * sc.y) : (v * sc.x + p * sc.y);
                    out[(size_t)(mbase + r) * 1024 + n] = f2bf(o);
                }
            }
        }
    } else {
        // V transposed: VT[b][n][pos]; 4 consecutive pos per quad -> ushort4
#pragma unroll
        for (int i = 0; i < 4; ++i) {
            const int mbase = m0 + wm + i * 16 + quad * 4;
            const int b = mbase >> 11, pos0 = mbase & 2047;
#pragma unroll
            for (int j = 0; j < 4; ++j) {
                const int n = n0 + wn + j * 16 + l16;
                ushort4 o;
                o.x = f2bf(acc[i][j][0]); o.y = f2bf(acc[i][j][1]);
                o.z = f2bf(acc[i][j][2]); o.w = f2bf(acc[i][j][3]);
                *(ushort4*)(VT + ((size_t)b * 1024 + n) * 2048 + pos0) = o;
            }
        }
    }
}

// scores: grid (16, 16, 4); lower tiles only; S fp32 scaled 1/32. Dbuf core.
__global__ __launch_bounds__(256) void scores_kernel(
    const ushort* __restrict__ Qr, const ushort* __restrict__ Kr,
    float* __restrict__ S)
{
    const int m0 = blockIdx.x * 128;
    const int n0 = blockIdx.y * 128;
    if (n0 > m0 + 127) return;
    const int b = blockIdx.z;
    __shared__ __attribute__((aligned(16))) ushort As[2 * 128 * 32];
    __shared__ __attribute__((aligned(16))) ushort Bs[2 * 128 * 32];
    const ushort* A = Qr + (size_t)b * 2048 * 1024;
    const ushort* B = Kr + (size_t)b * 2048 * 1024;
    float* Sb = S + (size_t)b * 2048 * 2048;

    f32x4 acc[4][4];
    ACC_INIT4(acc)
    gemm128_core_db(A, B, 1024, 1024, m0, n0, 32, As, Bs, acc);

    const int lane = threadIdx.x & 63, wave = threadIdx.x >> 6;
    const int wm = (wave >> 1) * 64, wn = (wave & 1) * 64;
    const int quad = lane >> 4, l16 = lane & 15;
#pragma unroll
    for (int i = 0; i < 4; ++i)
#pragma unroll
        for (int j = 0; j < 4; ++j) {
            const int n = n0 + wn + j * 16 + l16;
#pragma unroll
            for (int r = 0; r < 4; ++r) {
                const int m = m0 + wm + i * 16 + quad * 4 + r;
                Sb[(size_t)m * 2048 + n] = acc[i][j][r] * 0.03125f;
            }
        }
}

// Row softmax, register-staged, wave-parallel reduction (3 barriers).
// Reads clipped to nvalid; writes clipped to roundup(row+1,128)
// (pv's causal k-limit guarantees it never reads past that).
__global__ __launch_bounds__(256) void softmax_kernel(
    const float* __restrict__ S, ushort* __restrict__ P)
{
    __shared__ float red[4];
    const int row = blockIdx.x, tid = threadIdx.x, b = blockIdx.y;
    const int lane = tid & 63, wave = tid >> 6;
    const float* s = S + ((size_t)b * 2048 + row) * 2048;
    ushort*      p = P + ((size_t)b * 2048 + row) * 2048;
    const int nvalid = row + 1;
    const int wlimit = (row & ~127) + 128;
    const int j0 = tid * 8;

    float v[8] = {0.0f, 0.0f, 0.0f, 0.0f, 0.0f, 0.0f, 0.0f, 0.0f};
    if (j0 < nvalid) {
        float4 f0 = *(const float4*)(s + j0);
        v[0]=f0.x; v[1]=f0.y; v[2]=f0.z; v[3]=f0.w;
    }
    if (j0 + 4 < nvalid) {
        float4 f1 = *(const float4*)(s + j0 + 4);
        v[4]=f1.x; v[5]=f1.y; v[6]=f1.z; v[7]=f1.w;
    }

    float mx = -3.402823466e38f;
#pragma unroll
    for (int u = 0; u < 8; ++u) if (j0 + u < nvalid) mx = fmaxf(mx, v[u]);
#pragma unroll
    for (int d = 1; d < 64; d <<= 1) mx = fmaxf(mx, __shfl_xor(mx, d));
    if (lane == 0) red[wave] = mx;
    __syncthreads();
    mx = fmaxf(fmaxf(red[0], red[1]), fmaxf(red[2], red[3]));

    float sum = 0.0f;
#pragma unroll
    for (int u = 0; u < 8; ++u) {
        v[u] = (j0 + u < nvalid) ? __expf(v[u] - mx) : 0.0f;
        sum += v[u];
    }
#pragma unroll
    for (int d = 1; d < 64; d <<= 1) sum += __shfl_xor(sum, d);
    __syncthreads();                 // all reads of red done before overwrite
    if (lane == 0) red[wave] = sum;
    __syncthreads();
    const float inv = 1.0f / (red[0] + red[1] + red[2] + red[3]);

    if (j0 < wlimit) {
        ushort o[8];
#pragma unroll
        for (int u = 0; u < 8; ++u) o[u] = f2bf(v[u] * inv);
        *(int4*)(p + j0) = *(const int4*)o;
    }
}

// pv: grid (16, 8, 4); causal k-limit; dbuf core; m-tile interleave for
// K-balance (kIters 4..64 -> pair heavy with light in dispatch order).
__global__ __launch_bounds__(256) void pv_kernel(
    const ushort* __restrict__ P, const ushort* __restrict__ VT,
    float* __restrict__ out)
{
    __shared__ __attribute__((aligned(16))) ushort As[2 * 128 * 32];
    __shared__ __attribute__((aligned(16))) ushort Bs[2 * 128 * 32];
    const int x  = blockIdx.x;
    const int mt = (x & 1) ? (15 - (x >> 1)) : (x >> 1);  // 0,15,1,14,...
    const int m0 = mt * 128;
    const int n0 = blockIdx.y * 128;
    const int b  = blockIdx.z;
    const ushort* A = P + (size_t)b * 2048 * 2048;
    const ushort* B = VT + (size_t)b * 1024 * 2048;
    const int kIters = (m0 + 128) / 32;   // causal: P[m][k]=0 for k>m

    f32x4 acc[4][4];
    ACC_INIT4(acc)
    gemm128_core_db(A, B, 2048, 2048, m0, n0, kIters, As, Bs, acc);

    const int lane = threadIdx.x & 63, wave = threadIdx.x >> 6;
    const int wm = (wave >> 1) * 64, wn = (wave & 1) * 64;
    const int quad = lane >> 4, l16 = lane & 15;
#pragma unroll
    for (int i = 0; i < 4; ++i)
#pragma unroll
        for (int j = 0; j < 4; ++j) {
            const int n = n0 + wn + j * 16 + l16;
#pragma unroll
            for (int r = 0; r < 4; ++r) {
                const int m = m0 + wm + i * 16 + quad * 4 + r;
                out[((size_t)b * 2048 + m) * 1024 + n] = acc[i][j][r];
            }
        }
}

extern "C" void kernel_launch(void* const* d_in, const int* in_sizes, int n_in,
                              void* d_out, int out_size, void* d_ws, size_t ws_size,
                              hipStream_t stream) {
    const float* x  = (const float*)d_in[0];
    const float* wq = (const float*)d_in[1];
    const float* wk = (const float*)d_in[2];
    const float* wv = (const float*)d_in[3];

    const size_t MiB = 1024 * 1024;
    char* ws = (char*)d_ws;
    ushort* xb  = (ushort*)(ws);              //  16 MiB [8192][1024] bf16
    ushort* wqb = (ushort*)(ws +  16 * MiB);  //   2 MiB
    ushort* wkb = (ushort*)(ws +  18 * MiB);  //   2 MiB
    ushort* wvb = (ushort*)(ws +  20 * MiB);  //   2 MiB
    ushort* Qr  = (ushort*)(ws +  22 * MiB);  //  16 MiB [4][2048][1024] bf16
    ushort* Kr  = (ushort*)(ws +  38 * MiB);  //  16 MiB
    ushort* VT  = (ushort*)(ws +  54 * MiB);  //  16 MiB [4][1024][2048] bf16
    float*  S   = (float* )(ws +  70 * MiB);  //  64 MiB [4][2048][2048] f32
    ushort* P   = (ushort*)(ws + 134 * MiB);  //  32 MiB [4][2048][2048] bf16
    float2* cs  = (float2*)(ws + 166 * MiB);  //   8 MiB [2048][512] (cos,sin) f32
    float*  out = (float*)d_out;              // ws use: 174 MiB (256 avail)

    cvt_all_kernel <<<dim3(8192, 5),   256, 0, stream>>>(x, wq, wk, wv, xb, wqb, wkb, wvb, cs);
    qkv_rope_kernel<<<dim3(64, 8, 3),  256, 0, stream>>>(xb, wqb, wkb, wvb, cs, Qr, Kr, VT);
    scores_kernel  <<<dim3(16, 16, 4), 256, 0, stream>>>(Qr, Kr, S);
    softmax_kernel <<<dim3(2048, 4),   256, 0, stream>>>(S, P);
    pv_kernel      <<<dim3(16, 8, 4),  256, 0, stream>>>(P, VT, out);
}

// Round 7
// 257.441 us; speedup vs baseline: 1.2102x; 1.0671x over previous
//
#include <hip/hip_runtime.h>
#include <hip/hip_bf16.h>
#include <math.h>

// R17: BK=64 cores (barrier count halved). R16 state: all three GEMM kernels
// barrier-bound (MfmaUtil 21-24, VALU ~13, HBM <20% -> nothing saturated;
// 2 barriers per BK=32 step with ~150-200cyc compute vs ~200-400cyc drain).
// Schedule grafts on BK=32 all null/negative (R12/R14) -> change the
// structural parameter instead. Per K-step: 8 staging loads, one barrier
// pair, TWO ds_read+16-MFMA sub-phases (kk=0,1) reusing the same 8 fragment
// regs (VGPR ~flat; avoids m132's BK=128 occupancy death). LDS: qkv sb
// 32KB (5 blocks/CU); scores/pv db 64KB (2 blocks/CU = launch limit anyway).
// Swizzle generalized to 8 chunks: LDS[row][p] holds logical chunk
// p^(row&7); staging pre-swizzles GLOBAL col (lane l loads chunk
// (l&7)^(l>>3), lane-constant since group bases are 0 mod 8), LDS dest
// linear (m104/m173). Read: p=(kk*4|quad)^(l16&7). 8 lanes/chunk = b128
// bank minimum, conflict-free. k-order identical -> bitwise-same results.
// Kept: cvt+cos/sin table, wave-parallel softmax, clip, pv m-interleave.
// Known: qkv cross-run noise band 86-98us on identical code (+-7%).

typedef __bf16 bf16x8 __attribute__((ext_vector_type(8)));
typedef float  f32x4  __attribute__((ext_vector_type(4)));

__device__ __forceinline__ ushort f2bf(float f) {
    __hip_bfloat16 h = __float2bfloat16(f);
    return *reinterpret_cast<ushort*>(&h);
}

__device__ __forceinline__ void async_load16(const ushort* g, ushort* l) {
    __builtin_amdgcn_global_load_lds(
        (const __attribute__((address_space(1))) void*)g,
        (__attribute__((address_space(3))) void*)l, 16, 0, 0);
}

// One launch for all 4 fp32->bf16 conversions + RoPE cos/sin table.
// grid (8192, 5): y<4 = conversions, y==4 = table gen (first 4096 x-blocks).
__global__ __launch_bounds__(256) void cvt_all_kernel(
    const float* __restrict__ x,  const float* __restrict__ wq,
    const float* __restrict__ wk, const float* __restrict__ wv,
    ushort* __restrict__ xb, ushort* __restrict__ wqb,
    ushort* __restrict__ wkb, ushort* __restrict__ wvb,
    float2* __restrict__ cs)
{
    const int t = blockIdx.y;
    if (t == 4) {
        // RoPE table: cs[pos*512 + i] = (cos(pos*phi_i), sin(pos*phi_i)),
        // phi_i = 10000^(-2*(i-1)/1024)  (reference's -1 quirk preserved).
        const int idx = blockIdx.x * 256 + threadIdx.x;
        if (idx < 2048 * 512) {
            const int pos = idx >> 9, i = idx & 511;
            const float phi = powf(10000.0f, -2.0f * ((float)i - 1.0f) / 1024.0f);
            float s, c;
            sincosf((float)pos * phi, &s, &c);
            cs[idx] = make_float2(c, s);
        }
        return;
    }
    const float* in  = (t == 0) ? x  : (t == 1) ? wq  : (t == 2) ? wk  : wv;
    ushort*      out = (t == 0) ? xb : (t == 1) ? wqb : (t == 2) ? wkb : wvb;
    const int n4 = (t == 0) ? 2097152 : 262144;
    int i = blockIdx.x * blockDim.x + threadIdx.x;
    if (i < n4) {
        float4 f = ((const float4*)in)[i];
        ushort4 o;
        o.x = f2bf(f.x); o.y = f2bf(f.y); o.z = f2bf(f.z); o.w = f2bf(f.w);
        ((ushort4*)out)[i] = o;
    }
}

// ------------- single-buffer BK=64 core: high-occupancy kernels -----------
// LDS: As/Bs each [128][64] ushort (16 KB). One barrier pair per 64-K step.
__device__ __forceinline__ void gemm128_core_sb64(
    const ushort* __restrict__ A, const ushort* __restrict__ B,
    int lda, int ldb, int m0, int n0, int kIters,
    ushort* As, ushort* Bs, f32x4 acc[4][4])
{
    const int tid  = threadIdx.x;
    const int lane = tid & 63, wave = tid >> 6;
    const int wm = (wave >> 1) * 64, wn = (wave & 1) * 64;
    const int quad = lane >> 4, l16 = lane & 15;
    // staging: lane -> row group offset (lane>>3), physical chunk (lane&7);
    // global (logical) chunk = (lane&7)^(lane>>3) since base rows are 0 mod 8.
    const int srow8 = lane >> 3;
    const int gchk  = (lane & 7) ^ srow8;
    const ushort* ag = A + (size_t)(m0 + wave * 32 + srow8) * lda + gchk * 8;
    const ushort* bg = B + (size_t)(n0 + wave * 32 + srow8) * ldb + gchk * 8;
    // read: physical chunk for logical (kk*4|quad) at row r (r&7 == l16&7)
    const int p0 = quad ^ (l16 & 7);           // kk=0; kk=1 is p0^4

    for (int kt = 0; kt < kIters; ++kt) {
        const int k0 = kt * 64;
#pragma unroll
        for (int s = 0; s < 4; ++s) {
            async_load16(ag + k0 + (size_t)(s * 8) * lda,
                         As + (wave * 32 + s * 8) * 64);
            async_load16(bg + k0 + (size_t)(s * 8) * ldb,
                         Bs + (wave * 32 + s * 8) * 64);
        }
        __syncthreads();
#pragma unroll
        for (int kk = 0; kk < 2; ++kk) {
            const int poff = (p0 ^ (kk << 2)) * 8;
            bf16x8 aF[4], bF[4];
#pragma unroll
            for (int i = 0; i < 4; ++i)
                aF[i] = *(const bf16x8*)(As + (wm + i * 16 + l16) * 64 + poff);
#pragma unroll
            for (int j = 0; j < 4; ++j)
                bF[j] = *(const bf16x8*)(Bs + (wn + j * 16 + l16) * 64 + poff);
#pragma unroll
            for (int i = 0; i < 4; ++i)
#pragma unroll
                for (int j = 0; j < 4; ++j)
                    acc[i][j] = __builtin_amdgcn_mfma_f32_16x16x32_bf16(aF[i], bF[j], acc[i][j], 0, 0, 0);
        }
        __syncthreads();
    }
}

// ------------- double-buffered BK=64 core: low-occupancy kernels ----------
// LDS: As/Bs each [2][128][64] ushort (32 KB each, 64 KB total).
__device__ __forceinline__ void gemm128_core_db64(
    const ushort* __restrict__ A, const ushort* __restrict__ B,
    int lda, int ldb, int m0, int n0, int kIters,
    ushort* As, ushort* Bs, f32x4 acc[4][4])
{
    const int tid  = threadIdx.x;
    const int lane = tid & 63, wave = tid >> 6;
    const int wm = (wave >> 1) * 64, wn = (wave & 1) * 64;
    const int quad = lane >> 4, l16 = lane & 15;
    const int srow8 = lane >> 3;
    const int gchk  = (lane & 7) ^ srow8;
    const ushort* ag = A + (size_t)(m0 + wave * 32 + srow8) * lda + gchk * 8;
    const ushort* bg = B + (size_t)(n0 + wave * 32 + srow8) * ldb + gchk * 8;
    const int p0 = quad ^ (l16 & 7);

#define STAGE64(K0, NB) do {                                            \
        _Pragma("unroll")                                               \
        for (int s = 0; s < 4; ++s) {                                   \
            async_load16(ag + (K0) + (size_t)(s * 8) * lda,             \
                         As + (NB) + (wave * 32 + s * 8) * 64);         \
            async_load16(bg + (K0) + (size_t)(s * 8) * ldb,             \
                         Bs + (NB) + (wave * 32 + s * 8) * 64);         \
        }                                                               \
    } while (0)

    // Prologue: stage k-tile 0 into buffer 0.
    STAGE64(0, 0);
    __syncthreads();

    int cur = 0;
    for (int kt = 0; kt < kIters; ++kt) {
        if (kt + 1 < kIters) STAGE64((kt + 1) * 64, (cur ^ 1) * 8192);
        const ushort* as = As + cur * 8192;
        const ushort* bs = Bs + cur * 8192;
#pragma unroll
        for (int kk = 0; kk < 2; ++kk) {
            const int poff = (p0 ^ (kk << 2)) * 8;
            bf16x8 aF[4], bF[4];
#pragma unroll
            for (int i = 0; i < 4; ++i)
                aF[i] = *(const bf16x8*)(as + (wm + i * 16 + l16) * 64 + poff);
#pragma unroll
            for (int j = 0; j < 4; ++j)
                bF[j] = *(const bf16x8*)(bs + (wn + j * 16 + l16) * 64 + poff);
#pragma unroll
            for (int i = 0; i < 4; ++i)
#pragma unroll
                for (int j = 0; j < 4; ++j)
                    acc[i][j] = __builtin_amdgcn_mfma_f32_16x16x32_bf16(aF[i], bF[j], acc[i][j], 0, 0, 0);
        }
        __syncthreads();
        cur ^= 1;
    }
#undef STAGE64
}

#define ACC_INIT4(acc) \
    _Pragma("unroll") for (int i = 0; i < 4; ++i) \
    _Pragma("unroll") for (int j = 0; j < 4; ++j) \
    _Pragma("unroll") for (int r = 0; r < 4; ++r) acc[i][j][r] = 0.0f;

// QKV + RoPE, z-split. grid (64, 8, 3). sb64 core.
__global__ __launch_bounds__(256) void qkv_rope_kernel(
    const ushort* __restrict__ xb, const ushort* __restrict__ wq,
    const ushort* __restrict__ wk, const ushort* __restrict__ wv,
    const float2* __restrict__ cs,
    ushort* __restrict__ Qr, ushort* __restrict__ Kr, ushort* __restrict__ VT)
{
    __shared__ __attribute__((aligned(16))) ushort As[128 * 64];
    __shared__ __attribute__((aligned(16))) ushort Bs[128 * 64];
    const int m0 = blockIdx.x * 128;
    const int n0 = blockIdx.y * 128;
    const int z  = blockIdx.z;
    const ushort* W = (z == 0) ? wq : (z == 1) ? wk : wv;

    f32x4 acc[4][4];
    ACC_INIT4(acc)
    gemm128_core_sb64(xb, W, 1024, 1024, m0, n0, 16, As, Bs, acc);

    const int lane = threadIdx.x & 63, wave = threadIdx.x >> 6;
    const int wm = (wave >> 1) * 64, wn = (wave & 1) * 64;
    const int quad = lane >> 4, l16 = lane & 15;

    if (z < 2) {
        ushort* out = (z == 0) ? Qr : Kr;
#pragma unroll
        for (int j = 0; j < 4; ++j) {
            const int n = n0 + wn + j * 16 + l16;
            const int iidx = n >> 1;
            const bool odd = n & 1;
#pragma unroll
            for (int i = 0; i < 4; ++i) {
                const int mbase = m0 + wm + i * 16 + quad * 4;
                const int pos0  = mbase & 2047;
                const float2* csp = cs + (size_t)pos0 * 512 + iidx;
#pragma unroll
                for (int r = 0; r < 4; ++r) {
                    const float2 sc = csp[(size_t)r * 512]; // (cos, sin) at pos0+r
                    float v = acc[i][j][r];
                    float p = __shfl_xor(v, 1);   // partner column n^1, same row
                    float o = odd ? (v * sc.x - p * sc.y) : (v * sc.x + p * sc.y);
                    out[(size_t)(mbase + r) * 1024 + n] = f2bf(o);
                }
            }
        }
    } else {
        // V transposed: VT[b][n][pos]; 4 consecutive pos per quad -> ushort4
#pragma unroll
        for (int i = 0; i < 4; ++i) {
            const int mbase = m0 + wm + i * 16 + quad * 4;
            const int b = mbase >> 11, pos0 = mbase & 2047;
#pragma unroll
            for (int j = 0; j < 4; ++j) {
                const int n = n0 + wn + j * 16 + l16;
                ushort4 o;
                o.x = f2bf(acc[i][j][0]); o.y = f2bf(acc[i][j][1]);
                o.z = f2bf(acc[i][j][2]); o.w = f2bf(acc[i][j][3]);
                *(ushort4*)(VT + ((size_t)b * 1024 + n) * 2048 + pos0) = o;
            }
        }
    }
}

// scores: grid (16, 16, 4); lower tiles only; S fp32 scaled 1/32. db64 core.
__global__ __launch_bounds__(256) void scores_kernel(
    const ushort* __restrict__ Qr, const ushort* __restrict__ Kr,
    float* __restrict__ S)
{
    const int m0 = blockIdx.x * 128;
    const int n0 = blockIdx.y * 128;
    if (n0 > m0 + 127) return;
    const int b = blockIdx.z;
    __shared__ __attribute__((aligned(16))) ushort As[2 * 128 * 64];
    __shared__ __attribute__((aligned(16))) ushort Bs[2 * 128 * 64];
    const ushort* A = Qr + (size_t)b * 2048 * 1024;
    const ushort* B = Kr + (size_t)b * 2048 * 1024;
    float* Sb = S + (size_t)b * 2048 * 2048;

    f32x4 acc[4][4];
    ACC_INIT4(acc)
    gemm128_core_db64(A, B, 1024, 1024, m0, n0, 16, As, Bs, acc);

    const int lane = threadIdx.x & 63, wave = threadIdx.x >> 6;
    const int wm = (wave >> 1) * 64, wn = (wave & 1) * 64;
    const int quad = lane >> 4, l16 = lane & 15;
#pragma unroll
    for (int i = 0; i < 4; ++i)
#pragma unroll
        for (int j = 0; j < 4; ++j) {
            const int n = n0 + wn + j * 16 + l16;
#pragma unroll
            for (int r = 0; r < 4; ++r) {
                const int m = m0 + wm + i * 16 + quad * 4 + r;
                Sb[(size_t)m * 2048 + n] = acc[i][j][r] * 0.03125f;
            }
        }
}

// Row softmax, register-staged, wave-parallel reduction (3 barriers).
// Reads clipped to nvalid; writes clipped to roundup(row+1,128).
__global__ __launch_bounds__(256) void softmax_kernel(
    const float* __restrict__ S, ushort* __restrict__ P)
{
    __shared__ float red[4];
    const int row = blockIdx.x, tid = threadIdx.x, b = blockIdx.y;
    const int lane = tid & 63, wave = tid >> 6;
    const float* s = S + ((size_t)b * 2048 + row) * 2048;
    ushort*      p = P + ((size_t)b * 2048 + row) * 2048;
    const int nvalid = row + 1;
    const int wlimit = (row & ~127) + 128;
    const int j0 = tid * 8;

    float v[8] = {0.0f, 0.0f, 0.0f, 0.0f, 0.0f, 0.0f, 0.0f, 0.0f};
    if (j0 < nvalid) {
        float4 f0 = *(const float4*)(s + j0);
        v[0]=f0.x; v[1]=f0.y; v[2]=f0.z; v[3]=f0.w;
    }
    if (j0 + 4 < nvalid) {
        float4 f1 = *(const float4*)(s + j0 + 4);
        v[4]=f1.x; v[5]=f1.y; v[6]=f1.z; v[7]=f1.w;
    }

    float mx = -3.402823466e38f;
#pragma unroll
    for (int u = 0; u < 8; ++u) if (j0 + u < nvalid) mx = fmaxf(mx, v[u]);
#pragma unroll
    for (int d = 1; d < 64; d <<= 1) mx = fmaxf(mx, __shfl_xor(mx, d));
    if (lane == 0) red[wave] = mx;
    __syncthreads();
    mx = fmaxf(fmaxf(red[0], red[1]), fmaxf(red[2], red[3]));

    float sum = 0.0f;
#pragma unroll
    for (int u = 0; u < 8; ++u) {
        v[u] = (j0 + u < nvalid) ? __expf(v[u] - mx) : 0.0f;
        sum += v[u];
    }
#pragma unroll
    for (int d = 1; d < 64; d <<= 1) sum += __shfl_xor(sum, d);
    __syncthreads();                 // all reads of red done before overwrite
    if (lane == 0) red[wave] = sum;
    __syncthreads();
    const float inv = 1.0f / (red[0] + red[1] + red[2] + red[3]);

    if (j0 < wlimit) {
        ushort o[8];
#pragma unroll
        for (int u = 0; u < 8; ++u) o[u] = f2bf(v[u] * inv);
        *(int4*)(p + j0) = *(const int4*)o;
    }
}

// pv: grid (16, 8, 4); causal k-limit; db64 core; m-tile interleave.
__global__ __launch_bounds__(256) void pv_kernel(
    const ushort* __restrict__ P, const ushort* __restrict__ VT,
    float* __restrict__ out)
{
    __shared__ __attribute__((aligned(16))) ushort As[2 * 128 * 64];
    __shared__ __attribute__((aligned(16))) ushort Bs[2 * 128 * 64];
    const int x  = blockIdx.x;
    const int mt = (x & 1) ? (15 - (x >> 1)) : (x >> 1);  // 0,15,1,14,...
    const int m0 = mt * 128;
    const int n0 = blockIdx.y * 128;
    const int b  = blockIdx.z;
    const ushort* A = P + (size_t)b * 2048 * 2048;
    const ushort* B = VT + (size_t)b * 1024 * 2048;
    const int kIters = (m0 + 128) / 64;   // causal: P[m][k]=0 for k>m

    f32x4 acc[4][4];
    ACC_INIT4(acc)
    gemm128_core_db64(A, B, 2048, 2048, m0, n0, kIters, As, Bs, acc);

    const int lane = threadIdx.x & 63, wave = threadIdx.x >> 6;
    const int wm = (wave >> 1) * 64, wn = (wave & 1) * 64;
    const int quad = lane >> 4, l16 = lane & 15;
#pragma unroll
    for (int i = 0; i < 4; ++i)
#pragma unroll
        for (int j = 0; j < 4; ++j) {
            const int n = n0 + wn + j * 16 + l16;
#pragma unroll
            for (int r = 0; r < 4; ++r) {
                const int m = m0 + wm + i * 16 + quad * 4 + r;
                out[((size_t)b * 2048 + m) * 1024 + n] = acc[i][j][r];
            }
        }
}

extern "C" void kernel_launch(void* const* d_in, const int* in_sizes, int n_in,
                              void* d_out, int out_size, void* d_ws, size_t ws_size,
                              hipStream_t stream) {
    const float* x  = (const float*)d_in[0];
    const float* wq = (const float*)d_in[1];
    const float* wk = (const float*)d_in[2];
    const float* wv = (const float*)d_in[3];

    const size_t MiB = 1024 * 1024;
    char* ws = (char*)d_ws;
    ushort* xb  = (ushort*)(ws);              //  16 MiB [8192][1024] bf16
    ushort* wqb = (ushort*)(ws +  16 * MiB);  //   2 MiB
    ushort* wkb = (ushort*)(ws +  18 * MiB);  //   2 MiB
    ushort* wvb = (ushort*)(ws +  20 * MiB);  //   2 MiB
    ushort* Qr  = (ushort*)(ws +  22 * MiB);  //  16 MiB [4][2048][1024] bf16
    ushort* Kr  = (ushort*)(ws +  38 * MiB);  //  16 MiB
    ushort* VT  = (ushort*)(ws +  54 * MiB);  //  16 MiB [4][1024][2048] bf16
    float*  S   = (float* )(ws +  70 * MiB);  //  64 MiB [4][2048][2048] f32
    ushort* P   = (ushort*)(ws + 134 * MiB);  //  32 MiB [4][2048][2048] bf16
    float2* cs  = (float2*)(ws + 166 * MiB);  //   8 MiB [2048][512] (cos,sin) f32
    float*  out = (float*)d_out;              // ws use: 174 MiB (256 avail)

    cvt_all_kernel <<<dim3(8192, 5),   256, 0, stream>>>(x, wq, wk, wv, xb, wqb, wkb, wvb, cs);
    qkv_rope_kernel<<<dim3(64, 8, 3),  256, 0, stream>>>(xb, wqb, wkb, wvb, cs, Qr, Kr, VT);
    scores_kernel  <<<dim3(16, 16, 4), 256, 0, stream>>>(Qr, Kr, S);
    softmax_kernel <<<dim3(2048, 4),   256, 0, stream>>>(S, P);
    pv_kernel      <<<dim3(16, 8, 4),  256, 0, stream>>>(P, VT, out);
}